// Round 6
// baseline (107.972 us; speedup 1.0000x reference)
//
#include <hip/hip_runtime.h>
#include <math.h>

#define VOCAB 4096
#define NROWS 65536          // B*L = 4*16384
#define DECAYF 0.99f
#define EPSF 1e-5f
#define NSEG 8               // segment-sum privatization blocks

typedef unsigned long long u64;
typedef unsigned int u32;

// ---------------- ws layout (floats) ----------------
// [0,      32768)   pcnt[NSEG][4096]
// [32768,  131072)  pw[NSEG][12288]
// [131072, 131584)  errpart: 256 doubles
// [131584, 131586)  n_acc double
// total ~526 KB (proven ws >= 655 KB in round 4)

// Fused scan: block=1024 (16 waves), grid=256 (1 block/CU). Block packs the
// full embed table into 64 KB LDS as (-2e0,-2e1,-2e2,e2sum), lane owns 4 rows,
// wave w scans cands [w*256,(w+1)*256) via broadcast ds_read_b128 (1 read
// feeds 4 rows x 64 lanes). Exact np.argmin via u64 keys. No global atomics.
__global__ __launch_bounds__(1024, 4) void vq_scan_kernel(
    const float* __restrict__ feats,
    const float* __restrict__ embed,
    float* __restrict__ quant_out,
    float* __restrict__ idx_out,
    double* __restrict__ errpart) {
    #pragma clang fp contract(off)
    __shared__ float4 tab[VOCAB];          // 64 KB; aliased as merge scratch later

    const int tid  = threadIdx.x;
    const int wave = tid >> 6;
    const int lane = tid & 63;

    // stage + pack: thread t handles cands {t, t+1024, t+2048, t+3072}
    // (16 B/lane LDS write stride -> conflict-free; scalar embed loads coalesce)
    #pragma unroll
    for (int k = 0; k < 4; ++k) {
        const int c = tid + k * 1024;
        const float e0 = embed[c * 3 + 0];
        const float e1 = embed[c * 3 + 1];
        const float e2 = embed[c * 3 + 2];
        // numpy rounding: (e0^2 + e1^2) + e2^2, each product rounded
        const float e2s = (e0 * e0 + e1 * e1) + e2 * e2;
        tab[c] = make_float4(-2.0f * e0, -2.0f * e1, -2.0f * e2, e2s);
    }

    // lane's 4 rows: 48 B contiguous = 3x float4
    const int rbase = blockIdx.x * 256 + lane * 4;
    const float4 fa = *(const float4*)(feats + rbase * 3);
    const float4 fb = *(const float4*)(feats + rbase * 3 + 4);
    const float4 fc = *(const float4*)(feats + rbase * 3 + 8);
    float f0[4] = {fa.x, fa.w, fb.z, fc.y};
    float f1[4] = {fa.y, fb.x, fb.w, fc.z};
    float f2[4] = {fa.z, fb.y, fc.x, fc.w};
    float fs[4];
    #pragma unroll
    for (int r = 0; r < 4; ++r)
        fs[r] = (f0[r] * f0[r] + f1[r] * f1[r]) + f2[r] * f2[r];

    __syncthreads();

    float best[4] = {INFINITY, INFINITY, INFINITY, INFINITY};
    int   bj[4]   = {0, 0, 0, 0};
    const float4* __restrict__ wt = tab + (wave << 8);   // 256-cand slice

    #pragma unroll 4
    for (int j = 0; j < 256; ++j) {
        const float4 p = wt[j];            // broadcast ds_read_b128
        #pragma unroll
        for (int r = 0; r < 4; ++r) {
            // bit-identical to fmaf(e2,f2,fmaf(e1,f1,e0*f0)); then ref rounding
            float t = fmaf(p.z, f2[r], fmaf(p.y, f1[r], p.x * f0[r]));
            float d = (fs[r] + t) + p.w;   // == (fsum - 2*dot) + e2sum
            if (d < best[r]) { best[r] = d; bj[r] = j; }  // strict <: lowest j
        }
    }

    // exact-order keys: monotone(dist) high 32, global cand low 32
    const int w0 = wave << 8;
    u64 key[4];
    #pragma unroll
    for (int r = 0; r < 4; ++r) {
        u32 b = __float_as_uint(best[r]);
        u32 mb = b ^ ((u32)((int)b >> 31) | 0x80000000u);   // total order map
        key[r] = ((u64)mb << 32) | (u32)(w0 + bj[r]);
    }

    __syncthreads();                       // all waves done reading tab
    u64* mk = (u64*)tab;                   // [16][4][64] = 32 KB, aliases tab
    if (wave != 0) {
        #pragma unroll
        for (int r = 0; r < 4; ++r)
            mk[(wave * 4 + r) * 64 + lane] = key[r];   // 8B/lane stride: free
    }
    __syncthreads();
    if (wave == 0) {
        for (int w = 1; w < 16; ++w) {
            #pragma unroll
            for (int r = 0; r < 4; ++r) {
                u64 k = mk[(w * 4 + r) * 64 + lane];
                key[r] = k < key[r] ? k : key[r];
            }
        }
        int cand[4];
        #pragma unroll
        for (int r = 0; r < 4; ++r) cand[r] = (int)(u32)key[r];

        *(float4*)(idx_out + rbase) =
            make_float4((float)cand[0], (float)cand[1], (float)cand[2], (float)cand[3]);

        // quant = embed[cand] directly (exact; embed is L2-resident)
        float q[4][3];
        #pragma unroll
        for (int r = 0; r < 4; ++r) {
            q[r][0] = embed[cand[r] * 3 + 0];
            q[r][1] = embed[cand[r] * 3 + 1];
            q[r][2] = embed[cand[r] * 3 + 2];
        }
        *(float4*)(quant_out + rbase * 3)     = make_float4(q[0][0], q[0][1], q[0][2], q[1][0]);
        *(float4*)(quant_out + rbase * 3 + 4) = make_float4(q[1][1], q[1][2], q[2][0], q[2][1]);
        *(float4*)(quant_out + rbase * 3 + 8) = make_float4(q[2][2], q[3][0], q[3][1], q[3][2]);

        float err = 0.0f;
        #pragma unroll
        for (int r = 0; r < 4; ++r) {
            float d0 = q[r][0] - f0[r], d1 = q[r][1] - f1[r], d2 = q[r][2] - f2[r];
            err += d0 * d0 + d1 * d1 + d2 * d2;
        }
        #pragma unroll
        for (int off = 32; off >= 1; off >>= 1) err += __shfl_xor(err, off);
        if (lane == 0) errpart[blockIdx.x] = (double)err;
    }
}

// segment sums via LDS privatization: NSEG blocks x 1024 thr, each block
// accumulates 8192 rows into 64KB LDS (ds_add_f32), flushes plain stores.
__global__ __launch_bounds__(1024) void seg_kernel(
    const float* __restrict__ feats,
    const float* __restrict__ idx_f,
    float* __restrict__ pcnt,
    float* __restrict__ pw) {
    __shared__ float lcnt[VOCAB];          // 16 KB
    __shared__ float lw[VOCAB * 3];        // 48 KB
    const int t = threadIdx.x;
    const int b = blockIdx.x;

    #pragma unroll
    for (int i = 0; i < 4; ++i)  lcnt[t + i * 1024] = 0.0f;
    #pragma unroll
    for (int i = 0; i < 12; ++i) lw[t + i * 1024] = 0.0f;
    __syncthreads();

    #pragma unroll
    for (int i = 0; i < 8; ++i) {
        const int row = b * 8192 + i * 1024 + t;
        const int cand = (int)idx_f[row];
        const float f0 = feats[row * 3 + 0];
        const float f1 = feats[row * 3 + 1];
        const float f2 = feats[row * 3 + 2];
        atomicAdd(&lcnt[cand], 1.0f);
        atomicAdd(&lw[cand * 3 + 0], f0);
        atomicAdd(&lw[cand * 3 + 1], f1);
        atomicAdd(&lw[cand * 3 + 2], f2);
    }
    __syncthreads();

    #pragma unroll
    for (int i = 0; i < 4; ++i)  pcnt[b * VOCAB + t + i * 1024] = lcnt[t + i * 1024];
    #pragma unroll
    for (int i = 0; i < 12; ++i) pw[b * VOCAB * 3 + t + i * 1024] = lw[t + i * 1024];
}

__global__ __launch_bounds__(256) void ema_kernel(
    const float* __restrict__ ema_cs,
    const float* __restrict__ ema_w,
    const float* __restrict__ pcnt,
    const float* __restrict__ pw,
    float* __restrict__ ncs_out,
    float* __restrict__ nw_out,
    double* __restrict__ n_acc) {
    int v = blockIdx.x * 256 + threadIdx.x;
    if (v >= VOCAB) return;
    float c = 0.0f, w0 = 0.0f, w1 = 0.0f, w2 = 0.0f;
    for (int b = 0; b < NSEG; ++b) {       // ascending b = ascending row order
        c  += pcnt[b * VOCAB + v];
        w0 += pw[b * VOCAB * 3 + v * 3 + 0];
        w1 += pw[b * VOCAB * 3 + v * 3 + 1];
        w2 += pw[b * VOCAB * 3 + v * 3 + 2];
    }
    float ncs = DECAYF * ema_cs[v] + (1.0f - DECAYF) * c;
    ncs_out[v] = ncs;
    nw_out[v * 3 + 0] = DECAYF * ema_w[v * 3 + 0] + (1.0f - DECAYF) * w0;
    nw_out[v * 3 + 1] = DECAYF * ema_w[v * 3 + 1] + (1.0f - DECAYF) * w1;
    nw_out[v * 3 + 2] = DECAYF * ema_w[v * 3 + 2] + (1.0f - DECAYF) * w2;

    float s = ncs;
    #pragma unroll
    for (int off = 32; off >= 1; off >>= 1) s += __shfl_xor(s, off);
    if ((threadIdx.x & 63) == 0) atomicAdd(n_acc, (double)s);
}

__global__ __launch_bounds__(256) void final_kernel(
    const float* __restrict__ ncs,
    const float* __restrict__ nw,
    const double* __restrict__ n_acc,
    const double* __restrict__ errpart,
    float* __restrict__ embed_out,
    float* __restrict__ loss_out) {
    __shared__ double se[256];
    int v = blockIdx.x * 256 + threadIdx.x;
    if (v < VOCAB) {
        const float n = (float)(*n_acc);
        const float cs = (ncs[v] + EPSF) / (n + (float)VOCAB * EPSF) * n;
        const float d0 = nw[v * 3 + 0] / cs;
        const float d1 = nw[v * 3 + 1] / cs;
        const float d2 = nw[v * 3 + 2] / cs;
        const float nrm = fmaxf(sqrtf(d1 * d1 + d2 * d2), EPSF);
        embed_out[v * 3 + 0] = d0;
        embed_out[v * 3 + 1] = d1 / nrm;
        embed_out[v * 3 + 2] = d2 / nrm;
    }
    if (blockIdx.x == 0) {
        const int t = threadIdx.x;
        se[t] = errpart[t];                // 256 block partials
        __syncthreads();
        #pragma unroll
        for (int s = 128; s > 0; s >>= 1) {
            if (t < s) se[t] += se[t + s];
            __syncthreads();
        }
        if (t == 0)
            loss_out[0] = (float)(1.25 * se[0] / (double)(NROWS * 3));
    }
}

extern "C" void kernel_launch(void* const* d_in, const int* in_sizes, int n_in,
                              void* d_out, int out_size, void* d_ws, size_t ws_size,
                              hipStream_t stream) {
    const float* feats  = (const float*)d_in[0];   // 65536*3
    const float* embed  = (const float*)d_in[1];   // 4096*3
    const float* ema_cs = (const float*)d_in[2];   // 4096
    const float* ema_w  = (const float*)d_in[3];   // 4096*3

    float* out = (float*)d_out;
    float* quant_out = out;                         // 196608
    float* idx_out   = out + 196608;                // 65536
    float* loss_out  = out + 262144;                // 1
    float* embed_out = out + 262145;                // 12288
    float* ncs_out   = out + 274433;                // 4096
    float* nw_out    = out + 278529;                // 12288

    float* ws = (float*)d_ws;
    float*  pcnt    = ws;                           // NSEG*4096
    float*  pw      = ws + 32768;                   // NSEG*12288
    double* errpart = (double*)(ws + 131072);       // 256 doubles
    double* n_ac    = (double*)(ws + 131584);       // 1 double

    hipMemsetAsync(n_ac, 0, sizeof(double), stream);

    vq_scan_kernel<<<NROWS / 256, 1024, 0, stream>>>(feats, embed,
                                                     quant_out, idx_out, errpart);
    seg_kernel<<<NSEG, 1024, 0, stream>>>(feats, idx_out, pcnt, pw);
    ema_kernel<<<VOCAB / 256, 256, 0, stream>>>(ema_cs, ema_w, pcnt, pw,
                                                ncs_out, nw_out, n_ac);
    final_kernel<<<VOCAB / 256, 256, 0, stream>>>(ncs_out, nw_out, n_ac, errpart,
                                                  embed_out, loss_out);
}